// Round 1
// baseline (48149.936 us; speedup 1.0000x reference)
//
#include <hip/hip_runtime.h>

#define TPB 256

__device__ __forceinline__ float lrelu_f(float x) { return x > 0.f ? x : 0.2f * x; }
__device__ __forceinline__ float sigm_f(float x)  { return 1.f / (1.f + __expf(-x)); }

static inline int gridFor(int total) { return (total + TPB - 1) / TPB; }

// ---------------------------------------------------------------------------
// Stride-1 3x3 conv, pad (1,1), input = concat(X[Cx ch], H[Ch ch]) along C.
// ACT: 0 none, 1 sigmoid, 2 leaky-relu(0.2). 4 outputs per thread along W.
// ---------------------------------------------------------------------------
template<int ACT>
__global__ void conv3x3_s1_k(const float* __restrict__ X, int xStrideN,
                             const float* __restrict__ H,
                             const float* __restrict__ Wt, const float* __restrict__ Bias,
                             float* __restrict__ Out,
                             int N, int Cx, int Ch, int Co, int HH, int WW)
{
    const int Ci = Cx + Ch;
    const int Wq = WW >> 2;
    const int total = N * Co * HH * Wq;
    int idx = blockIdx.x * blockDim.x + threadIdx.x;
    if (idx >= total) return;
    const int ow0 = (idx % Wq) << 2;
    int r = idx / Wq;
    const int oh = r % HH; r /= HH;
    const int co = r % Co;
    const int n  = r / Co;

    float a0 = 0.f, a1 = 0.f, a2 = 0.f, a3 = 0.f;
    const float* wb = Wt + (size_t)co * Ci * 9;
    const bool interior = (ow0 > 0) && (ow0 + 4 < WW);
    const int HWi = HH * WW;

    for (int ci = 0; ci < Ci; ++ci) {
        const float* src = (ci < Cx)
            ? (X + (size_t)n * xStrideN + (size_t)ci * HWi)
            : (H + ((size_t)n * Ch + (size_t)(ci - Cx)) * HWi);
        const float* w = wb + ci * 9;
        const float w0=w[0],w1=w[1],w2=w[2],w3=w[3],w4=w[4],w5=w[5],w6=w[6],w7=w[7],w8=w[8];
        #pragma unroll
        for (int kh = 0; kh < 3; ++kh) {
            const int ih = oh + kh - 1;
            if ((unsigned)ih >= (unsigned)HH) continue;
            const float* row = src + ih * WW + ow0;
            float v0,v1,v2,v3,v4,v5;
            if (interior) {
                v0=row[-1]; v1=row[0]; v2=row[1]; v3=row[2]; v4=row[3]; v5=row[4];
            } else {
                v0 = (ow0 > 0)      ? row[-1] : 0.f;
                v1=row[0]; v2=row[1]; v3=row[2]; v4=row[3];
                v5 = (ow0 + 4 < WW) ? row[4]  : 0.f;
            }
            float wk0, wk1, wk2;
            if      (kh == 0) { wk0=w0; wk1=w1; wk2=w2; }
            else if (kh == 1) { wk0=w3; wk1=w4; wk2=w5; }
            else              { wk0=w6; wk1=w7; wk2=w8; }
            a0 += v0*wk0 + v1*wk1 + v2*wk2;
            a1 += v1*wk0 + v2*wk1 + v3*wk2;
            a2 += v2*wk0 + v3*wk1 + v4*wk2;
            a3 += v3*wk0 + v4*wk1 + v5*wk2;
        }
    }
    const float b = Bias[co];
    a0 += b; a1 += b; a2 += b; a3 += b;
    if (ACT == 1) { a0=sigm_f(a0); a1=sigm_f(a1); a2=sigm_f(a2); a3=sigm_f(a3); }
    else if (ACT == 2) { a0=lrelu_f(a0); a1=lrelu_f(a1); a2=lrelu_f(a2); a3=lrelu_f(a3); }
    *reinterpret_cast<float4*>(Out + (((size_t)n*Co + co)*HH + oh)*WW + ow0)
        = make_float4(a0,a1,a2,a3);
}

// ---------------------------------------------------------------------------
// Stride-2 3x3 conv, pad (0,1) per JAX SAME (even in, out=in/2), fused lrelu.
// ---------------------------------------------------------------------------
__global__ void conv3x3_s2_lrelu_k(const float* __restrict__ X, int xStrideN,
                                   const float* __restrict__ Wt, const float* __restrict__ Bias,
                                   float* __restrict__ Out,
                                   int N, int Ci, int Co, int Ho, int Wo)
{
    const int Hi = Ho << 1, Wi = Wo << 1;
    const int Wq = Wo >> 2;
    const int total = N * Co * Ho * Wq;
    int idx = blockIdx.x * blockDim.x + threadIdx.x;
    if (idx >= total) return;
    const int ow0 = (idx % Wq) << 2;
    int r = idx / Wq;
    const int oh = r % Ho; r /= Ho;
    const int co = r % Co;
    const int n  = r / Co;

    const int iwb = ow0 << 1;
    const bool wedge = (ow0 + 4 == Wo);   // col iwb+8 == Wi on the last quad
    float a0=0.f,a1=0.f,a2=0.f,a3=0.f;
    const float* wb = Wt + (size_t)co * Ci * 9;
    const int HWi = Hi * Wi;

    for (int ci = 0; ci < Ci; ++ci) {
        const float* src = X + (size_t)n * xStrideN + (size_t)ci * HWi;
        const float* w = wb + ci * 9;
        const float w0=w[0],w1=w[1],w2=w[2],w3=w[3],w4=w[4],w5=w[5],w6=w[6],w7=w[7],w8=w[8];
        #pragma unroll
        for (int kh = 0; kh < 3; ++kh) {
            const int ih = (oh << 1) + kh;
            if (ih >= Hi) continue;
            const float* row = src + ih * Wi + iwb;
            const float v0=row[0],v1=row[1],v2=row[2],v3=row[3],v4=row[4],v5=row[5],v6=row[6],v7=row[7];
            const float v8 = wedge ? 0.f : row[8];
            float wk0, wk1, wk2;
            if      (kh == 0) { wk0=w0; wk1=w1; wk2=w2; }
            else if (kh == 1) { wk0=w3; wk1=w4; wk2=w5; }
            else              { wk0=w6; wk1=w7; wk2=w8; }
            a0 += v0*wk0 + v1*wk1 + v2*wk2;
            a1 += v2*wk0 + v3*wk1 + v4*wk2;
            a2 += v4*wk0 + v5*wk1 + v6*wk2;
            a3 += v6*wk0 + v7*wk1 + v8*wk2;
        }
    }
    const float b = Bias[co];
    a0=lrelu_f(a0+b); a1=lrelu_f(a1+b); a2=lrelu_f(a2+b); a3=lrelu_f(a3+b);
    *reinterpret_cast<float4*>(Out + (((size_t)n*Co + co)*Ho + oh)*Wo + ow0)
        = make_float4(a0,a1,a2,a3);
}

// ---------------------------------------------------------------------------
// Transposed conv, stride 2, kernel 4x4, JAX SAME (lhs_dilation=2, pad (2,2)),
// fused lrelu. out[o] = sum over kh with (o-2+kh) even of in[(o-2+kh)/2]*w[kh].
// Per output row-parity: kh in {p, p+2}, ih_a = (oh>>1)-1+p, ih_b = ih_a+1.
// ---------------------------------------------------------------------------
__global__ void deconv4x4_s2_lrelu_k(const float* __restrict__ X,
                                     const float* __restrict__ Wt, const float* __restrict__ Bias,
                                     float* __restrict__ Out,
                                     int N, int Ci, int Co, int Ho, int Wo)
{
    const int Hi = Ho >> 1, Wi = Wo >> 1;
    const int Wq = Wo >> 2;
    const int total = N * Co * Ho * Wq;
    int idx = blockIdx.x * blockDim.x + threadIdx.x;
    if (idx >= total) return;
    const int ow0 = (idx % Wq) << 2;
    int r = idx / Wq;
    const int oh = r % Ho; r /= Ho;
    const int co = r % Co;
    const int n  = r / Co;

    const int hpar = oh & 1;
    const int ih_a = (oh >> 1) - 1 + hpar;
    const int ih_b = ih_a + 1;
    const bool aok = (ih_a >= 0);
    const bool bok = (ih_b < Hi);
    const int kh_a = hpar, kh_b = hpar + 2;
    const int iw0 = (ow0 >> 1) - 1;          // cols iw0..iw0+3 needed
    const bool c0ok = (iw0 >= 0);
    const bool c3ok = (iw0 + 3 < Wi);
    const int HWi = Hi * Wi;

    float a0=0.f,a1=0.f,a2=0.f,a3=0.f;
    for (int ci = 0; ci < Ci; ++ci) {
        const float* src = X + ((size_t)n*Ci + ci) * HWi;
        const float* w = Wt + ((size_t)co*Ci + ci) * 16;
        const float wa0=w[kh_a*4+0], wa1=w[kh_a*4+1], wa2=w[kh_a*4+2], wa3=w[kh_a*4+3];
        const float wb0=w[kh_b*4+0], wb1=w[kh_b*4+1], wb2=w[kh_b*4+2], wb3=w[kh_b*4+3];
        const float* rowa = src + ih_a*Wi + iw0;
        const float* rowb = src + ih_b*Wi + iw0;
        const float va0 = (aok && c0ok) ? rowa[0] : 0.f;
        const float va1 =  aok          ? rowa[1] : 0.f;
        const float va2 =  aok          ? rowa[2] : 0.f;
        const float va3 = (aok && c3ok) ? rowa[3] : 0.f;
        const float vb0 = (bok && c0ok) ? rowb[0] : 0.f;
        const float vb1 =  bok          ? rowb[1] : 0.f;
        const float vb2 =  bok          ? rowb[2] : 0.f;
        const float vb3 = (bok && c3ok) ? rowb[3] : 0.f;
        // even outputs use kw {0,2}, odd outputs kw {1,3}
        a0 += va0*wa0 + va1*wa2 + vb0*wb0 + vb1*wb2;
        a1 += va1*wa1 + va2*wa3 + vb1*wb1 + vb2*wb3;
        a2 += va1*wa0 + va2*wa2 + vb1*wb0 + vb2*wb2;
        a3 += va2*wa1 + va3*wa3 + vb2*wb1 + vb3*wb3;
    }
    const float b = Bias[co];
    a0=lrelu_f(a0+b); a1=lrelu_f(a1+b); a2=lrelu_f(a2+b); a3=lrelu_f(a3+b);
    *reinterpret_cast<float4*>(Out + (((size_t)n*Co + co)*Ho + oh)*Wo + ow0)
        = make_float4(a0,a1,a2,a3);
}

// rh[n,c,p] = g[n, Ch+c, p] * h[n,c,p]   (g has 2*Ch channels: [z, r])
__global__ void rh_k(const float* __restrict__ g, const float* __restrict__ h,
                     float* __restrict__ out, int N, int Ch, int HW)
{
    const int total = N * Ch * HW;
    int i = blockIdx.x * blockDim.x + threadIdx.x;
    if (i >= total) return;
    const int n = i / (Ch * HW);
    const float rr = g[(size_t)i + (size_t)(n + 1) * Ch * HW];
    out[i] = rr * h[i];
}

// h = (1-z)*h + z*cand, z = g[n, c, p]
__global__ void update_k(const float* __restrict__ g, const float* __restrict__ cnd,
                         float* __restrict__ h, int N, int Ch, int HW)
{
    const int total = N * Ch * HW;
    int i = blockIdx.x * blockDim.x + threadIdx.x;
    if (i >= total) return;
    const int n = i / (Ch * HW);
    const float z = g[(size_t)i + (size_t)n * Ch * HW];
    const float hv = h[i];
    h[i] = (1.f - z) * hv + z * cnd[i];
}

// ---------------------------------------------------------------------------
extern "C" void kernel_launch(void* const* d_in, const int* in_sizes, int n_in,
                              void* d_out, int out_size, void* d_ws, size_t ws_size,
                              hipStream_t stream)
{
    const float* h1    = (const float*)d_in[0];
    const float* h2    = (const float*)d_in[1];
    const float* h3    = (const float*)d_in[2];
    const float* y     = (const float*)d_in[3];
    const float* ew1   = (const float*)d_in[4];  const float* eb1 = (const float*)d_in[5];
    const float* ew2   = (const float*)d_in[6];  const float* eb2 = (const float*)d_in[7];
    const float* ew3   = (const float*)d_in[8];  const float* eb3 = (const float*)d_in[9];
    const float* g3wg  = (const float*)d_in[10]; const float* g3bg = (const float*)d_in[11];
    const float* g3wc  = (const float*)d_in[12]; const float* g3bc = (const float*)d_in[13];
    const float* g2wg  = (const float*)d_in[14]; const float* g2bg = (const float*)d_in[15];
    const float* g2wc  = (const float*)d_in[16]; const float* g2bc = (const float*)d_in[17];
    const float* g1wg  = (const float*)d_in[18]; const float* g1bg = (const float*)d_in[19];
    const float* g1wc  = (const float*)d_in[20]; const float* g1bc = (const float*)d_in[21];
    const float* s3w   = (const float*)d_in[22]; const float* s3b  = (const float*)d_in[23];
    const float* s2w   = (const float*)d_in[24]; const float* s2b  = (const float*)d_in[25];
    const float* s1w   = (const float*)d_in[26]; const float* s1b  = (const float*)d_in[27];
    const float* hwt   = (const float*)d_in[28]; const float* hbs  = (const float*)d_in[29];
    float* out = (float*)d_out;

    float* ws = (float*)d_ws;
    size_t off = 0;
    auto alloc = [&](size_t nf) { float* p = ws + off; off += nf; return p; };
    float* e3   = alloc((size_t)160*96*576);       // [T*B,96,24,24] encoder output
    float* be1  = alloc((size_t)16*16*96*96);      // encoder chunk scratch
    float* be2  = alloc((size_t)16*64*48*48);
    float* c3   = alloc((size_t)16*96*576);        // GRU states
    float* c2   = alloc((size_t)16*64*2304);
    float* c1   = alloc((size_t)16*16*9216);
    float* gbuf = alloc((size_t)16*128*2304);      // shared gates buffer (max level)
    float* cnd  = alloc((size_t)16*64*2304);       // shared candidate buffer
    float* rh   = alloc((size_t)16*64*2304);       // shared r*h buffer
    float* obuf = alloc((size_t)16*8*36864);       // shared deconv-output buffer
    (void)ws_size; (void)in_sizes; (void)n_in; (void)out_size;

    const int T = 10;

    // init states from inputs (inputs are restored before every launch)
    hipMemcpyAsync(c1, h1, (size_t)16*16*9216*sizeof(float), hipMemcpyDeviceToDevice, stream);
    hipMemcpyAsync(c2, h2, (size_t)16*64*2304*sizeof(float), hipMemcpyDeviceToDevice, stream);
    hipMemcpyAsync(c3, h3, (size_t)16*96*576 *sizeof(float), hipMemcpyDeviceToDevice, stream);

    // ---------------- encoder: per t, frames b=0..15 ----------------
    for (int t = 0; t < T; ++t) {
        const float* yb = y + (size_t)t * 36864;   // y[b,t] at b*T*HW + t*HW
        conv3x3_s2_lrelu_k<<<gridFor(16*16*96*24), TPB, 0, stream>>>(
            yb, 10*36864, ew1, eb1, be1, 16, 1, 16, 96, 96);
        conv3x3_s2_lrelu_k<<<gridFor(16*64*48*12), TPB, 0, stream>>>(
            be1, 16*9216, ew2, eb2, be2, 16, 16, 64, 48, 48);
        conv3x3_s2_lrelu_k<<<gridFor(16*96*24*6), TPB, 0, stream>>>(
            be2, 64*2304, ew3, eb3, e3 + (size_t)t*16*96*576, 16, 64, 96, 24, 24);
    }

    // ---------------- scan over T steps ----------------
    for (int t = 0; t < T; ++t) {
        const float* x3 = e3 + (size_t)t * 16*96*576;

        // GRU3 @ 24x24 (state 96ch, input 96ch)
        conv3x3_s1_k<1><<<gridFor(16*192*24*6), TPB, 0, stream>>>(
            x3, 96*576, c3, g3wg, g3bg, gbuf, 16, 96, 96, 192, 24, 24);
        rh_k<<<gridFor(16*96*576), TPB, 0, stream>>>(gbuf, c3, rh, 16, 96, 576);
        conv3x3_s1_k<2><<<gridFor(16*96*24*6), TPB, 0, stream>>>(
            x3, 96*576, rh, g3wc, g3bc, cnd, 16, 96, 96, 96, 24, 24);
        update_k<<<gridFor(16*96*576), TPB, 0, stream>>>(gbuf, cnd, c3, 16, 96, 576);
        deconv4x4_s2_lrelu_k<<<gridFor(16*64*48*12), TPB, 0, stream>>>(
            c3, s3w, s3b, obuf, 16, 96, 64, 48, 48);

        // GRU2 @ 48x48 (state 64ch, input 64ch)
        conv3x3_s1_k<1><<<gridFor(16*128*48*12), TPB, 0, stream>>>(
            obuf, 64*2304, c2, g2wg, g2bg, gbuf, 16, 64, 64, 128, 48, 48);
        rh_k<<<gridFor(16*64*2304), TPB, 0, stream>>>(gbuf, c2, rh, 16, 64, 2304);
        conv3x3_s1_k<2><<<gridFor(16*64*48*12), TPB, 0, stream>>>(
            obuf, 64*2304, rh, g2wc, g2bc, cnd, 16, 64, 64, 64, 48, 48);
        update_k<<<gridFor(16*64*2304), TPB, 0, stream>>>(gbuf, cnd, c2, 16, 64, 2304);
        deconv4x4_s2_lrelu_k<<<gridFor(16*16*96*24), TPB, 0, stream>>>(
            c2, s2w, s2b, obuf, 16, 64, 16, 96, 96);

        // GRU1 @ 96x96 (state 16ch, input 16ch)
        conv3x3_s1_k<1><<<gridFor(16*32*96*24), TPB, 0, stream>>>(
            obuf, 16*9216, c1, g1wg, g1bg, gbuf, 16, 16, 16, 32, 96, 96);
        rh_k<<<gridFor(16*16*9216), TPB, 0, stream>>>(gbuf, c1, rh, 16, 16, 9216);
        conv3x3_s1_k<2><<<gridFor(16*16*96*24), TPB, 0, stream>>>(
            obuf, 16*9216, rh, g1wc, g1bc, cnd, 16, 16, 16, 16, 96, 96);
        update_k<<<gridFor(16*16*9216), TPB, 0, stream>>>(gbuf, cnd, c1, 16, 16, 9216);
        deconv4x4_s2_lrelu_k<<<gridFor(16*8*192*48), TPB, 0, stream>>>(
            c1, s1w, s1b, obuf, 16, 16, 8, 192, 192);

        // head conv -> output slice [B,1,192,192] at t
        conv3x3_s1_k<0><<<gridFor(16*1*192*48), TPB, 0, stream>>>(
            obuf, 8*36864, (const float*)nullptr, hwt, hbs,
            out + (size_t)t * 16 * 36864, 16, 8, 0, 1, 192, 192);
    }
}

// Round 3
// 26388.596 us; speedup vs baseline: 1.8246x; 1.8246x over previous
//
#include <hip/hip_runtime.h>

__device__ __forceinline__ float lrelu_f(float x) { return x > 0.f ? x : 0.2f * x; }
__device__ __forceinline__ float sigm_f(float x)  { return 1.f / (1.f + __expf(-x)); }

__host__ __device__ static inline int imin(int a, int b) { return a < b ? a : b; }

// ---------------------------------------------------------------------------
// Tiled stride-1 3x3 conv, pad (1,1). Input = concat(X[Cx], H[Ch]) on C.
// Block: 256 threads, one (n, co-block, spatial tile of <=256 quads).
// Per ci: stage haloed tile into LDS, each thread computes 4 outputs x CO_BLK.
// ACT: 0 none, 1 sigmoid, 2 lrelu.
// ---------------------------------------------------------------------------
template<int ACT, int CO_BLK>
__global__ __launch_bounds__(256) void conv3x3_s1_t(
    const float* __restrict__ X, int xStrideN,
    const float* __restrict__ Hs,
    const float* __restrict__ Wt, const float* __restrict__ Bias,
    float* __restrict__ Out,
    int Cx, int Ch, int Co, int HH, int WW)
{
    extern __shared__ float lds[];
    const int tile = blockIdx.x, co0 = blockIdx.y * CO_BLK, n = blockIdx.z;
    const int Ci = Cx + Ch;
    const int HW = HH * WW;
    const int quads = HW >> 2;
    const int q0 = tile << 8;
    const int nq = imin(256, quads - q0);
    const int tid = threadIdx.x;
    const int r_first = (q0 << 2) / WW;
    const int r_last  = (((q0 + nq - 1) << 2) + 3) / WW;
    const int rs0 = r_first - 1;
    const int nrows = r_last - r_first + 3;
    const int W2 = WW + 2;
    const int nst = nrows * W2;

    int oh = 0, ow0 = 0, lbase = 0;
    if (tid < nq) {
        const int p = (q0 + tid) << 2;
        oh = p / WW; ow0 = p - oh * WW;
        lbase = (oh - r_first) * W2 + ow0;   // LDS idx of (row oh-1, col ow0-1)
    }

    float acc[CO_BLK][4];
    #pragma unroll
    for (int j = 0; j < CO_BLK; ++j) { acc[j][0]=acc[j][1]=acc[j][2]=acc[j][3]=0.f; }

    for (int ci = 0; ci < Ci; ++ci) {
        const float* src = (ci < Cx)
            ? (X + (size_t)n * xStrideN + (size_t)ci * HW)
            : (Hs + ((size_t)n * Ch + (size_t)(ci - Cx)) * HW);
        __syncthreads();
        for (int i = tid; i < nst; i += 256) {
            const int lr = i / W2, c = i - lr * W2;
            const int gr = rs0 + lr, gc = c - 1;
            float v = 0.f;
            if ((unsigned)gr < (unsigned)HH && (unsigned)gc < (unsigned)WW)
                v = src[gr * WW + gc];
            lds[i] = v;
        }
        __syncthreads();
        if (tid >= nq) continue;

        float v0[6], v1[6], v2[6];
        const float* l0 = lds + lbase;
        #pragma unroll
        for (int x = 0; x < 6; ++x) {
            v0[x] = l0[x]; v1[x] = l0[W2 + x]; v2[x] = l0[2 * W2 + x];
        }
        const float* wb = Wt + ((size_t)co0 * Ci + ci) * 9;
        #pragma unroll
        for (int j = 0; j < CO_BLK; ++j) {
            const float* w = wb + (size_t)j * Ci * 9;
            const float w0=w[0],w1=w[1],w2=w[2],w3=w[3],w4=w[4],
                        w5=w[5],w6=w[6],w7=w[7],w8=w[8];
            #pragma unroll
            for (int x = 0; x < 4; ++x)
                acc[j][x] += v0[x]*w0 + v0[x+1]*w1 + v0[x+2]*w2
                           + v1[x]*w3 + v1[x+1]*w4 + v1[x+2]*w5
                           + v2[x]*w6 + v2[x+1]*w7 + v2[x+2]*w8;
        }
    }
    if (tid >= nq) return;
    #pragma unroll
    for (int j = 0; j < CO_BLK; ++j) {
        const float b = Bias[co0 + j];
        float4 o;
        o.x = acc[j][0] + b; o.y = acc[j][1] + b;
        o.z = acc[j][2] + b; o.w = acc[j][3] + b;
        if (ACT == 1) { o.x=sigm_f(o.x); o.y=sigm_f(o.y); o.z=sigm_f(o.z); o.w=sigm_f(o.w); }
        else if (ACT == 2) { o.x=lrelu_f(o.x); o.y=lrelu_f(o.y); o.z=lrelu_f(o.z); o.w=lrelu_f(o.w); }
        *reinterpret_cast<float4*>(Out + ((size_t)n * Co + co0 + j) * HW + ((q0 + tid) << 2)) = o;
    }
}

// ---------------------------------------------------------------------------
// Tiled stride-2 3x3 conv, pad (0,1), fused lrelu. (JAX SAME, even dims.)
// ---------------------------------------------------------------------------
template<int CO_BLK>
__global__ __launch_bounds__(256) void conv3x3_s2_t(
    const float* __restrict__ X, int xStrideN,
    const float* __restrict__ Wt, const float* __restrict__ Bias,
    float* __restrict__ Out, int Ci, int Co, int Ho, int Wo)
{
    extern __shared__ float lds[];
    const int Hi = Ho << 1, Wi = Wo << 1;
    const int tile = blockIdx.x, co0 = blockIdx.y * CO_BLK, n = blockIdx.z;
    const int quads = (Ho * Wo) >> 2;
    const int q0 = tile << 8;
    const int nq = imin(256, quads - q0);
    const int tid = threadIdx.x;
    const int r_first = (q0 << 2) / Wo;
    const int r_last  = (((q0 + nq - 1) << 2) + 3) / Wo;
    const int irs0 = r_first << 1;
    const int nrows = (r_last << 1) + 3 - irs0;
    const int W1 = Wi + 1;
    const int nst = nrows * W1;
    const int HWi = Hi * Wi;

    int oh = 0, ow0 = 0;
    if (tid < nq) { const int p = (q0 + tid) << 2; oh = p / Wo; ow0 = p - oh * Wo; }
    const int lbase = ((oh << 1) - irs0) * W1 + (ow0 << 1);

    float acc[CO_BLK][4];
    #pragma unroll
    for (int j = 0; j < CO_BLK; ++j) { acc[j][0]=acc[j][1]=acc[j][2]=acc[j][3]=0.f; }

    for (int ci = 0; ci < Ci; ++ci) {
        const float* src = X + (size_t)n * xStrideN + (size_t)ci * HWi;
        __syncthreads();
        for (int i = tid; i < nst; i += 256) {
            const int lr = i / W1, c = i - lr * W1;
            const int gr = irs0 + lr;
            float v = 0.f;
            if (gr < Hi && c < Wi) v = src[gr * Wi + c];
            lds[i] = v;
        }
        __syncthreads();
        if (tid >= nq) continue;

        float u0[9], u1[9], u2[9];
        const float* l0 = lds + lbase;
        #pragma unroll
        for (int x = 0; x < 9; ++x) {
            u0[x] = l0[x]; u1[x] = l0[W1 + x]; u2[x] = l0[2 * W1 + x];
        }
        const float* wb = Wt + ((size_t)co0 * Ci + ci) * 9;
        #pragma unroll
        for (int j = 0; j < CO_BLK; ++j) {
            const float* w = wb + (size_t)j * Ci * 9;
            const float w0=w[0],w1=w[1],w2=w[2],w3=w[3],w4=w[4],
                        w5=w[5],w6=w[6],w7=w[7],w8=w[8];
            #pragma unroll
            for (int x = 0; x < 4; ++x)
                acc[j][x] += u0[2*x]*w0 + u0[2*x+1]*w1 + u0[2*x+2]*w2
                           + u1[2*x]*w3 + u1[2*x+1]*w4 + u1[2*x+2]*w5
                           + u2[2*x]*w6 + u2[2*x+1]*w7 + u2[2*x+2]*w8;
        }
    }
    if (tid >= nq) return;
    #pragma unroll
    for (int j = 0; j < CO_BLK; ++j) {
        const float b = Bias[co0 + j];
        float4 o;
        o.x = lrelu_f(acc[j][0] + b); o.y = lrelu_f(acc[j][1] + b);
        o.z = lrelu_f(acc[j][2] + b); o.w = lrelu_f(acc[j][3] + b);
        *reinterpret_cast<float4*>(Out + ((size_t)n * Co + co0 + j) * (size_t)(Ho * Wo)
                                   + ((q0 + tid) << 2)) = o;
    }
}

// ---------------------------------------------------------------------------
// Tiled transposed conv 4x4 stride 2 (JAX SAME), fused lrelu.
// ---------------------------------------------------------------------------
template<int CO_BLK>
__global__ __launch_bounds__(256) void deconv4x4_s2_t(
    const float* __restrict__ X,
    const float* __restrict__ Wt, const float* __restrict__ Bias,
    float* __restrict__ Out, int Ci, int Co, int Ho, int Wo)
{
    extern __shared__ float lds[];
    const int Hi = Ho >> 1, Wi = Wo >> 1;
    const int tile = blockIdx.x, co0 = blockIdx.y * CO_BLK, n = blockIdx.z;
    const int quads = (Ho * Wo) >> 2;
    const int q0 = tile << 8;
    const int nq = imin(256, quads - q0);
    const int tid = threadIdx.x;
    const int r_first = (q0 << 2) / Wo;
    const int r_last  = (((q0 + nq - 1) << 2) + 3) / Wo;
    const int irs0 = (r_first >> 1) - 1;
    const int nrows = (r_last >> 1) + 1 - irs0 + 1;
    const int W2 = Wi + 2;
    const int nst = nrows * W2;
    const int HWi = Hi * Wi;

    int oh = 0, ow0 = 0;
    if (tid < nq) { const int p = (q0 + tid) << 2; oh = p / Wo; ow0 = p - oh * Wo; }
    const int hpar = oh & 1;
    const int ih_a = (oh >> 1) - 1 + hpar;
    const int la = (ih_a - irs0) * W2 + (ow0 >> 1);

    float acc[CO_BLK][4];
    #pragma unroll
    for (int j = 0; j < CO_BLK; ++j) { acc[j][0]=acc[j][1]=acc[j][2]=acc[j][3]=0.f; }

    for (int ci = 0; ci < Ci; ++ci) {
        const float* src = X + ((size_t)n * Ci + ci) * HWi;
        __syncthreads();
        for (int i = tid; i < nst; i += 256) {
            const int lr = i / W2, c = i - lr * W2;
            const int gr = irs0 + lr, gc = c - 1;
            float v = 0.f;
            if ((unsigned)gr < (unsigned)Hi && (unsigned)gc < (unsigned)Wi)
                v = src[gr * Wi + gc];
            lds[i] = v;
        }
        __syncthreads();
        if (tid >= nq) continue;

        const float va0 = lds[la],      va1 = lds[la+1],
                    va2 = lds[la+2],    va3 = lds[la+3];
        const float vb0 = lds[la+W2],   vb1 = lds[la+W2+1],
                    vb2 = lds[la+W2+2], vb3 = lds[la+W2+3];
        const float4* wq = reinterpret_cast<const float4*>(
            Wt + ((size_t)co0 * Ci + ci) * 16);
        #pragma unroll
        for (int j = 0; j < CO_BLK; ++j) {
            const float4 wA = wq[j * Ci * 4 + hpar];
            const float4 wB = wq[j * Ci * 4 + hpar + 2];
            acc[j][0] += va0*wA.x + va1*wA.z + vb0*wB.x + vb1*wB.z;
            acc[j][1] += va1*wA.y + va2*wA.w + vb1*wB.y + vb2*wB.w;
            acc[j][2] += va1*wA.x + va2*wA.z + vb1*wB.x + vb2*wB.z;
            acc[j][3] += va2*wA.y + va3*wA.w + vb2*wB.y + vb3*wB.w;
        }
    }
    if (tid >= nq) return;
    #pragma unroll
    for (int j = 0; j < CO_BLK; ++j) {
        const float b = Bias[co0 + j];
        float4 o;
        o.x = lrelu_f(acc[j][0] + b); o.y = lrelu_f(acc[j][1] + b);
        o.z = lrelu_f(acc[j][2] + b); o.w = lrelu_f(acc[j][3] + b);
        *reinterpret_cast<float4*>(Out + ((size_t)n * Co + co0 + j) * (size_t)(Ho * Wo)
                                   + ((q0 + tid) << 2)) = o;
    }
}

// rh[n,c,p] = g[n, Ch+c, p] * h[n,c,p]
__global__ void rh_k(const float* __restrict__ g, const float* __restrict__ h,
                     float* __restrict__ out, int N, int Ch, int HW)
{
    const int total = N * Ch * HW;
    int i = blockIdx.x * blockDim.x + threadIdx.x;
    if (i >= total) return;
    const int n = i / (Ch * HW);
    out[i] = g[(size_t)i + (size_t)(n + 1) * Ch * HW] * h[i];
}

// h = (1-z)*h + z*cand
__global__ void update_k(const float* __restrict__ g, const float* __restrict__ cnd,
                         float* __restrict__ h, int N, int Ch, int HW)
{
    const int total = N * Ch * HW;
    int i = blockIdx.x * blockDim.x + threadIdx.x;
    if (i >= total) return;
    const int n = i / (Ch * HW);
    const float z = g[(size_t)i + (size_t)n * Ch * HW];
    h[i] = (1.f - z) * h[i] + z * cnd[i];
}

// ---------------------------------------------------------------------------
extern "C" void kernel_launch(void* const* d_in, const int* in_sizes, int n_in,
                              void* d_out, int out_size, void* d_ws, size_t ws_size,
                              hipStream_t stream)
{
    const float* h1    = (const float*)d_in[0];
    const float* h2    = (const float*)d_in[1];
    const float* h3    = (const float*)d_in[2];
    const float* y     = (const float*)d_in[3];
    const float* ew1   = (const float*)d_in[4];  const float* eb1 = (const float*)d_in[5];
    const float* ew2   = (const float*)d_in[6];  const float* eb2 = (const float*)d_in[7];
    const float* ew3   = (const float*)d_in[8];  const float* eb3 = (const float*)d_in[9];
    const float* g3wg  = (const float*)d_in[10]; const float* g3bg = (const float*)d_in[11];
    const float* g3wc  = (const float*)d_in[12]; const float* g3bc = (const float*)d_in[13];
    const float* g2wg  = (const float*)d_in[14]; const float* g2bg = (const float*)d_in[15];
    const float* g2wc  = (const float*)d_in[16]; const float* g2bc = (const float*)d_in[17];
    const float* g1wg  = (const float*)d_in[18]; const float* g1bg = (const float*)d_in[19];
    const float* g1wc  = (const float*)d_in[20]; const float* g1bc = (const float*)d_in[21];
    const float* s3w   = (const float*)d_in[22]; const float* s3b  = (const float*)d_in[23];
    const float* s2w   = (const float*)d_in[24]; const float* s2b  = (const float*)d_in[25];
    const float* s1w   = (const float*)d_in[26]; const float* s1b  = (const float*)d_in[27];
    const float* hwt   = (const float*)d_in[28]; const float* hbs  = (const float*)d_in[29];
    float* out = (float*)d_out;

    float* ws = (float*)d_ws;
    size_t off = 0;
    auto alloc = [&](size_t nf) { float* p = ws + off; off += nf; return p; };
    float* e3   = alloc((size_t)160*96*576);
    float* be1  = alloc((size_t)16*16*96*96);
    float* be2  = alloc((size_t)16*64*48*48);
    float* c3   = alloc((size_t)16*96*576);
    float* c2   = alloc((size_t)16*64*2304);
    float* c1   = alloc((size_t)16*16*9216);
    float* gbuf = alloc((size_t)16*128*2304);
    float* cnd  = alloc((size_t)16*64*2304);
    float* rh   = alloc((size_t)16*64*2304);
    float* obuf = alloc((size_t)16*8*36864);
    (void)ws_size; (void)in_sizes; (void)n_in; (void)out_size;

    const int T = 10;

    (void)hipMemcpyAsync(c1, h1, (size_t)16*16*9216*sizeof(float), hipMemcpyDeviceToDevice, stream);
    (void)hipMemcpyAsync(c2, h2, (size_t)16*64*2304*sizeof(float), hipMemcpyDeviceToDevice, stream);
    (void)hipMemcpyAsync(c3, h3, (size_t)16*96*576 *sizeof(float), hipMemcpyDeviceToDevice, stream);

    // launch helpers -------------------------------------------------------
    auto s1 = [&](int act, const float* X, int xsn, const float* Hp,
                  const float* Wt, const float* Bs, float* O,
                  int Cx, int Ch, int Co, int Hh, int Ww) {
        const int quads = Hh * Ww / 4;
        const int tiles = (quads + 255) / 256;
        const int nrowsMax = imin(Hh + 2, 1024 / Ww + 4);
        const size_t smem = (size_t)nrowsMax * (Ww + 2) * sizeof(float);
        dim3 g(tiles, Co / 8, 16);
        if (act == 1)
            conv3x3_s1_t<1,8><<<g,256,smem,stream>>>(X,xsn,Hp,Wt,Bs,O,Cx,Ch,Co,Hh,Ww);
        else
            conv3x3_s1_t<2,8><<<g,256,smem,stream>>>(X,xsn,Hp,Wt,Bs,O,Cx,Ch,Co,Hh,Ww);
    };
    auto s2c = [&](const float* X, int xsn, const float* Wt, const float* Bs,
                   float* O, int Ci, int Co, int Ho, int Wo) {
        const int quads = Ho * Wo / 4;
        const int tiles = (quads + 255) / 256;
        const int outSpan = imin(Ho, 1024 / Wo + 2);
        const size_t smem = (size_t)(2 * outSpan + 1) * (2 * Wo + 1) * sizeof(float);
        dim3 g(tiles, Co / 8, 16);
        conv3x3_s2_t<8><<<g,256,smem,stream>>>(X,xsn,Wt,Bs,O,Ci,Co,Ho,Wo);
    };
    auto dcv = [&](const float* X, const float* Wt, const float* Bs,
                   float* O, int Ci, int Co, int Ho, int Wo) {
        const int quads = Ho * Wo / 4;
        const int tiles = (quads + 255) / 256;
        const int outSpan = imin(Ho, 1024 / Wo + 2);
        const size_t smem = (size_t)(outSpan / 2 + 4) * (Wo / 2 + 2) * sizeof(float);
        dim3 g(tiles, Co / 8, 16);
        deconv4x4_s2_t<8><<<g,256,smem,stream>>>(X,Wt,Bs,O,Ci,Co,Ho,Wo);
    };

    // ---------------- encoder ----------------
    for (int t = 0; t < T; ++t) {
        s2c(y + (size_t)t*36864, 10*36864, ew1, eb1, be1, 1, 16, 96, 96);
        s2c(be1, 16*9216,  ew2, eb2, be2, 16, 64, 48, 48);
        s2c(be2, 64*2304,  ew3, eb3, e3 + (size_t)t*16*96*576, 64, 96, 24, 24);
    }

    // ---------------- scan ----------------
    for (int t = 0; t < T; ++t) {
        const float* x3 = e3 + (size_t)t * 16*96*576;

        // GRU3 @ 24x24
        s1(1, x3, 96*576, c3, g3wg, g3bg, gbuf, 96, 96, 192, 24, 24);
        rh_k<<<(16*96*576+255)/256, 256, 0, stream>>>(gbuf, c3, rh, 16, 96, 576);
        s1(2, x3, 96*576, rh, g3wc, g3bc, cnd, 96, 96, 96, 24, 24);
        update_k<<<(16*96*576+255)/256, 256, 0, stream>>>(gbuf, cnd, c3, 16, 96, 576);
        dcv(c3, s3w, s3b, obuf, 96, 64, 48, 48);

        // GRU2 @ 48x48
        s1(1, obuf, 64*2304, c2, g2wg, g2bg, gbuf, 64, 64, 128, 48, 48);
        rh_k<<<(16*64*2304+255)/256, 256, 0, stream>>>(gbuf, c2, rh, 16, 64, 2304);
        s1(2, obuf, 64*2304, rh, g2wc, g2bc, cnd, 64, 64, 64, 48, 48);
        update_k<<<(16*64*2304+255)/256, 256, 0, stream>>>(gbuf, cnd, c2, 16, 64, 2304);
        dcv(c2, s2w, s2b, obuf, 64, 16, 96, 96);

        // GRU1 @ 96x96
        s1(1, obuf, 16*9216, c1, g1wg, g1bg, gbuf, 16, 16, 32, 96, 96);
        rh_k<<<(16*16*9216+255)/256, 256, 0, stream>>>(gbuf, c1, rh, 16, 16, 9216);
        s1(2, obuf, 16*9216, rh, g1wc, g1bc, cnd, 16, 16, 16, 96, 96);
        update_k<<<(16*16*9216+255)/256, 256, 0, stream>>>(gbuf, cnd, c1, 16, 16, 9216);
        dcv(c1, s1w, s1b, obuf, 16, 8, 192, 192);

        // head conv (Co=1)
        {
            const int quads = 192*192/4, tiles = (quads + 255) / 256;
            const size_t smem = (size_t)9 * 194 * sizeof(float);
            dim3 g(tiles, 1, 16);
            conv3x3_s1_t<0,1><<<g,256,smem,stream>>>(
                obuf, 8*36864, (const float*)nullptr, hwt, hbs,
                out + (size_t)t*16*36864, 8, 0, 1, 192, 192);
        }
    }
}

// Round 4
// 9990.096 us; speedup vs baseline: 4.8198x; 2.6415x over previous
//
#include <hip/hip_runtime.h>

typedef unsigned short ushort_t;
typedef __attribute__((ext_vector_type(8))) short short8v;
typedef __attribute__((ext_vector_type(4))) float f32x4;

__device__ __forceinline__ float lrelu_f(float x) { return x > 0.f ? x : 0.2f * x; }
__device__ __forceinline__ float sigm_f(float x)  { return 1.f / (1.f + __expf(-x)); }

__device__ __forceinline__ ushort_t bf16r(float f) {
    union { float f; unsigned int u; } x; x.f = f;
    unsigned int r = x.u + 0x7FFFu + ((x.u >> 16) & 1u);
    return (ushort_t)(r >> 16);
}

__host__ __device__ static inline int imin(int a, int b) { return a < b ? a : b; }

// ===========================================================================
// MFMA implicit-GEMM 3x3 stride-1 conv, pad(1,1), input concat(X[Cx],H[Ch])
// NHWC bf16 activations, output NHWC f32. K = 9*(Cx+Ch), k = tap*Ci + c.
// A-frag: lane holds X[pix = l&15][k=(l>>4)*8+m] (16B load, channels contig).
// B-frag: weights pre-swizzled [k/8][Co][8] so lane load is 16B contig.
// D: col(co)=l&15, row(pix)=(l>>4)*4+r  [m89-verified mapping].
// Block = 4 waves; wave owns MT M-tiles x NTB N-tiles; B K-chunk in LDS.
// ===========================================================================
template<int H, int W, int Cx, int Ch, int Co, int MT, int NTB, int KC, int ACT>
__global__ __launch_bounds__(256) void conv3x3_mfma(
    const ushort_t* __restrict__ Xp, const ushort_t* __restrict__ Hp,
    const ushort_t* __restrict__ Wf, const float* __restrict__ Bias,
    float* __restrict__ Out)
{
    constexpr int Ci = Cx + Ch;
    constexpr int K  = 9 * Ci;
    constexpr int HW = H * W;
    constexpr int NCO = NTB * 16;
    static_assert(K % KC == 0 && KC % 32 == 0, "KC");
    extern __shared__ ushort_t bsh[];

    const int tid = threadIdx.x;
    const int wv = tid >> 6, ln = tid & 63;
    const int llo = ln & 15, lhi = ln >> 4;
    const int co0 = blockIdx.y * NCO;

    int rowb[MT][9];
    unsigned vmask[MT];
    #pragma unroll
    for (int mt = 0; mt < MT; ++mt) {
        const int mtile = (blockIdx.x * 4 + wv) * MT + mt;
        const int gp = mtile * 16 + llo;
        const int n = gp / HW, p = gp % HW;
        const int hh = p / W, wc = p % W;
        vmask[mt] = 0u;
        #pragma unroll
        for (int tap = 0; tap < 9; ++tap) {
            const int dh = tap / 3 - 1, dw = tap % 3 - 1;
            const int h2 = hh + dh, w2 = wc + dw;
            rowb[mt][tap] = (n * H + h2) * W + w2;
            if ((unsigned)h2 < (unsigned)H && (unsigned)w2 < (unsigned)W)
                vmask[mt] |= 1u << tap;
        }
    }

    f32x4 acc[MT][NTB];
    #pragma unroll
    for (int mt = 0; mt < MT; ++mt)
        #pragma unroll
        for (int nt = 0; nt < NTB; ++nt)
            acc[mt][nt] = f32x4{0.f, 0.f, 0.f, 0.f};

    constexpr int NCH = K / KC;
    for (int ch = 0; ch < NCH; ++ch) {
        __syncthreads();
        constexpr int UNITS = (KC / 8) * NCO;     // 16B units
        for (int u = tid; u < UNITS; u += 256) {
            const int kb = u / NCO, col = u % NCO;
            const ushort_t* src = Wf + ((size_t)(ch * (KC / 8) + kb) * Co + co0 + col) * 8;
            *reinterpret_cast<short8v*>(&bsh[(size_t)u * 8]) =
                *reinterpret_cast<const short8v*>(src);
        }
        __syncthreads();

        #pragma unroll
        for (int kk = 0; kk < KC / 32; ++kk) {
            const int gk = ch * KC + kk * 32;
            const int tap = gk / Ci;
            const int cb  = gk % Ci;
            const int c   = cb + lhi * 8;

            short8v a[MT];
            #pragma unroll
            for (int mt = 0; mt < MT; ++mt) {
                a[mt] = short8v{0,0,0,0,0,0,0,0};
                if ((vmask[mt] >> tap) & 1u) {
                    const int rb = rowb[mt][tap];
                    const ushort_t* ap = (c < Cx)
                        ? (Xp + (size_t)rb * Cx + c)
                        : (Hp + (size_t)rb * Ch + (c - Cx));
                    a[mt] = *reinterpret_cast<const short8v*>(ap);
                }
            }
            #pragma unroll
            for (int nt = 0; nt < NTB; ++nt) {
                const short8v b = *reinterpret_cast<const short8v*>(
                    &bsh[((size_t)(kk * 4 + lhi) * NCO + nt * 16 + llo) * 8]);
                #pragma unroll
                for (int mt = 0; mt < MT; ++mt)
                    acc[mt][nt] = __builtin_amdgcn_mfma_f32_16x16x32_bf16(
                        a[mt], b, acc[mt][nt], 0, 0, 0);
            }
        }
    }

    #pragma unroll
    for (int mt = 0; mt < MT; ++mt) {
        const int mtile = (blockIdx.x * 4 + wv) * MT + mt;
        #pragma unroll
        for (int nt = 0; nt < NTB; ++nt) {
            const int co = co0 + nt * 16 + llo;
            const float bias = Bias[co];
            #pragma unroll
            for (int r = 0; r < 4; ++r) {
                const int opix = mtile * 16 + lhi * 4 + r;
                float v = acc[mt][nt][r] + bias;
                if (ACT == 1) v = sigm_f(v); else v = lrelu_f(v);
                Out[(size_t)opix * Co + co] = v;
            }
        }
    }
}

// ===========================================================================
// Weight swizzle: OIHW f32 -> [k/8][Co][8] bf16, k = tap*Ci + ci
// ===========================================================================
template<int CiT, int Co>
__global__ void wprep_k(const float* __restrict__ Wsrc, ushort_t* __restrict__ Wf)
{
    const int total = 9 * CiT * Co;
    int i = blockIdx.x * blockDim.x + threadIdx.x;
    if (i >= total) return;
    const int k = i / Co, co = i % Co;
    const int tap = k / CiT, ci = k % CiT;
    Wf[(size_t)(k >> 3) * Co * 8 + co * 8 + (k & 7)] =
        bf16r(Wsrc[((size_t)co * CiT + ci) * 9 + tap]);
}

// init: NCHW f32 input state -> NHWC f32 master + NHWC bf16 + NCHW f32 copy
template<int Ch, int HW>
__global__ void init_state_k(const float* __restrict__ src,
                             float* __restrict__ hm, ushort_t* __restrict__ hb,
                             float* __restrict__ hn)
{
    const int total = 16 * Ch * HW;
    int i = blockIdx.x * blockDim.x + threadIdx.x;
    if (i >= total) return;
    const int n = i / (Ch * HW);
    const int rem = i % (Ch * HW);
    const int c = rem / HW, p = rem % HW;
    const float v = src[i];
    const size_t pix = (size_t)n * HW + p;
    hm[pix * Ch + c] = v;
    hb[pix * Ch + c] = bf16r(v);
    hn[i] = v;
}

// rh = r*h (NHWC): r = g[pix][Ch+c], out bf16 NHWC
template<int Ch>
__global__ void rh_t(const float* __restrict__ g, const float* __restrict__ hm,
                     ushort_t* __restrict__ rhb, int total)
{
    int i = blockIdx.x * blockDim.x + threadIdx.x;
    if (i >= total) return;
    const int pix = i / Ch, c = i % Ch;
    const float r = g[(size_t)pix * 2 * Ch + Ch + c];
    rhb[i] = bf16r(r * hm[i]);
}

// h' = (1-z)h + z*cand; writes NHWC f32 + NHWC bf16 + NCHW f32
template<int Ch, int HW>
__global__ void upd_t(const float* __restrict__ g, const float* __restrict__ cnd,
                      float* __restrict__ hm, ushort_t* __restrict__ hb,
                      float* __restrict__ hn)
{
    const int total = 16 * HW * Ch;
    int i = blockIdx.x * blockDim.x + threadIdx.x;
    if (i >= total) return;
    const int pix = i / Ch, c = i % Ch;
    const float z = g[(size_t)pix * 2 * Ch + c];
    const float nh = (1.f - z) * hm[i] + z * cnd[i];
    hm[i] = nh;
    hb[i] = bf16r(nh);
    const int n = pix / HW, p = pix % HW;
    hn[((size_t)n * Ch + c) * HW + p] = nh;
}

// ===========================================================================
// fp32 tiled stride-1 conv (kept for head), stride-2 conv, deconv
// ===========================================================================
template<int ACT, int CO_BLK>
__global__ __launch_bounds__(256) void conv3x3_s1_t(
    const float* __restrict__ X, int xStrideN,
    const float* __restrict__ Hs,
    const float* __restrict__ Wt, const float* __restrict__ Bias,
    float* __restrict__ Out,
    int Cx, int Ch, int Co, int HH, int WW)
{
    extern __shared__ float lds[];
    const int tile = blockIdx.x, co0 = blockIdx.y * CO_BLK, n = blockIdx.z;
    const int Ci = Cx + Ch;
    const int HW = HH * WW;
    const int quads = HW >> 2;
    const int q0 = tile << 8;
    const int nq = imin(256, quads - q0);
    const int tid = threadIdx.x;
    const int r_first = (q0 << 2) / WW;
    const int r_last  = (((q0 + nq - 1) << 2) + 3) / WW;
    const int rs0 = r_first - 1;
    const int nrows = r_last - r_first + 3;
    const int W2 = WW + 2;
    const int nst = nrows * W2;

    int oh = 0, ow0 = 0, lbase = 0;
    if (tid < nq) {
        const int p = (q0 + tid) << 2;
        oh = p / WW; ow0 = p - oh * WW;
        lbase = (oh - r_first) * W2 + ow0;
    }

    float acc[CO_BLK][4];
    #pragma unroll
    for (int j = 0; j < CO_BLK; ++j) { acc[j][0]=acc[j][1]=acc[j][2]=acc[j][3]=0.f; }

    for (int ci = 0; ci < Ci; ++ci) {
        const float* src = (ci < Cx)
            ? (X + (size_t)n * xStrideN + (size_t)ci * HW)
            : (Hs + ((size_t)n * Ch + (size_t)(ci - Cx)) * HW);
        __syncthreads();
        for (int i = tid; i < nst; i += 256) {
            const int lr = i / W2, c = i - lr * W2;
            const int gr = rs0 + lr, gc = c - 1;
            float v = 0.f;
            if ((unsigned)gr < (unsigned)HH && (unsigned)gc < (unsigned)WW)
                v = src[gr * WW + gc];
            lds[i] = v;
        }
        __syncthreads();
        if (tid >= nq) continue;

        float v0[6], v1[6], v2[6];
        const float* l0 = lds + lbase;
        #pragma unroll
        for (int x = 0; x < 6; ++x) {
            v0[x] = l0[x]; v1[x] = l0[W2 + x]; v2[x] = l0[2 * W2 + x];
        }
        const float* wb = Wt + ((size_t)co0 * Ci + ci) * 9;
        #pragma unroll
        for (int j = 0; j < CO_BLK; ++j) {
            const float* w = wb + (size_t)j * Ci * 9;
            const float w0=w[0],w1=w[1],w2=w[2],w3=w[3],w4=w[4],
                        w5=w[5],w6=w[6],w7=w[7],w8=w[8];
            #pragma unroll
            for (int x = 0; x < 4; ++x)
                acc[j][x] += v0[x]*w0 + v0[x+1]*w1 + v0[x+2]*w2
                           + v1[x]*w3 + v1[x+1]*w4 + v1[x+2]*w5
                           + v2[x]*w6 + v2[x+1]*w7 + v2[x+2]*w8;
        }
    }
    if (tid >= nq) return;
    #pragma unroll
    for (int j = 0; j < CO_BLK; ++j) {
        const float b = Bias[co0 + j];
        float4 o;
        o.x = acc[j][0] + b; o.y = acc[j][1] + b;
        o.z = acc[j][2] + b; o.w = acc[j][3] + b;
        if (ACT == 1) { o.x=sigm_f(o.x); o.y=sigm_f(o.y); o.z=sigm_f(o.z); o.w=sigm_f(o.w); }
        else if (ACT == 2) { o.x=lrelu_f(o.x); o.y=lrelu_f(o.y); o.z=lrelu_f(o.z); o.w=lrelu_f(o.w); }
        *reinterpret_cast<float4*>(Out + ((size_t)n * Co + co0 + j) * HW + ((q0 + tid) << 2)) = o;
    }
}

// OMODE: 0 = NCHW f32, 1 = NHWC bf16 (CO_BLK must be 8)
template<int CO_BLK, int OMODE>
__global__ __launch_bounds__(256) void conv3x3_s2_t(
    const float* __restrict__ X, int xStrideN,
    const float* __restrict__ Wt, const float* __restrict__ Bias,
    void* __restrict__ Ov, int Ci, int Co, int Ho, int Wo)
{
    extern __shared__ float lds[];
    const int Hi = Ho << 1, Wi = Wo << 1;
    const int tile = blockIdx.x, co0 = blockIdx.y * CO_BLK, n = blockIdx.z;
    const int quads = (Ho * Wo) >> 2;
    const int q0 = tile << 8;
    const int nq = imin(256, quads - q0);
    const int tid = threadIdx.x;
    const int r_first = (q0 << 2) / Wo;
    const int r_last  = (((q0 + nq - 1) << 2) + 3) / Wo;
    const int irs0 = r_first << 1;
    const int nrows = (r_last << 1) + 3 - irs0;
    const int W1 = Wi + 1;
    const int nst = nrows * W1;
    const int HWi = Hi * Wi;

    int oh = 0, ow0 = 0;
    if (tid < nq) { const int p = (q0 + tid) << 2; oh = p / Wo; ow0 = p - oh * Wo; }
    const int lbase = ((oh << 1) - irs0) * W1 + (ow0 << 1);

    float acc[CO_BLK][4];
    #pragma unroll
    for (int j = 0; j < CO_BLK; ++j) { acc[j][0]=acc[j][1]=acc[j][2]=acc[j][3]=0.f; }

    for (int ci = 0; ci < Ci; ++ci) {
        const float* src = X + (size_t)n * xStrideN + (size_t)ci * HWi;
        __syncthreads();
        for (int i = tid; i < nst; i += 256) {
            const int lr = i / W1, c = i - lr * W1;
            const int gr = irs0 + lr;
            float v = 0.f;
            if (gr < Hi && c < Wi) v = src[gr * Wi + c];
            lds[i] = v;
        }
        __syncthreads();
        if (tid >= nq) continue;

        float u0[9], u1[9], u2[9];
        const float* l0 = lds + lbase;
        #pragma unroll
        for (int x = 0; x < 9; ++x) {
            u0[x] = l0[x]; u1[x] = l0[W1 + x]; u2[x] = l0[2 * W1 + x];
        }
        const float* wb = Wt + ((size_t)co0 * Ci + ci) * 9;
        #pragma unroll
        for (int j = 0; j < CO_BLK; ++j) {
            const float* w = wb + (size_t)j * Ci * 9;
            const float w0=w[0],w1=w[1],w2=w[2],w3=w[3],w4=w[4],
                        w5=w[5],w6=w[6],w7=w[7],w8=w[8];
            #pragma unroll
            for (int x = 0; x < 4; ++x)
                acc[j][x] += u0[2*x]*w0 + u0[2*x+1]*w1 + u0[2*x+2]*w2
                           + u1[2*x]*w3 + u1[2*x+1]*w4 + u1[2*x+2]*w5
                           + u2[2*x]*w6 + u2[2*x+1]*w7 + u2[2*x+2]*w8;
        }
    }
    if (tid >= nq) return;
    if (OMODE == 0) {
        float* Out = (float*)Ov;
        #pragma unroll
        for (int j = 0; j < CO_BLK; ++j) {
            const float b = Bias[co0 + j];
            float4 o;
            o.x = lrelu_f(acc[j][0] + b); o.y = lrelu_f(acc[j][1] + b);
            o.z = lrelu_f(acc[j][2] + b); o.w = lrelu_f(acc[j][3] + b);
            *reinterpret_cast<float4*>(Out + ((size_t)n * Co + co0 + j) * (size_t)(Ho * Wo)
                                       + ((q0 + tid) << 2)) = o;
        }
    } else {
        ushort_t* Ob = (ushort_t*)Ov;
        #pragma unroll
        for (int x = 0; x < 4; ++x) {
            short8v pk;
            #pragma unroll
            for (int j = 0; j < CO_BLK; ++j)
                pk[j] = (short)bf16r(lrelu_f(acc[j][x] + Bias[co0 + j]));
            const size_t pix = (size_t)n * (Ho * Wo) + ((q0 + tid) << 2) + x;
            *reinterpret_cast<short8v*>(Ob + pix * Co + co0) = pk;
        }
    }
}

// OMODE: 0 = NCHW f32, 1 = NHWC bf16 (CO_BLK must be 8)
template<int CO_BLK, int OMODE>
__global__ __launch_bounds__(256) void deconv4x4_s2_t(
    const float* __restrict__ X,
    const float* __restrict__ Wt, const float* __restrict__ Bias,
    void* __restrict__ Ov, int Ci, int Co, int Ho, int Wo)
{
    extern __shared__ float lds[];
    const int Hi = Ho >> 1, Wi = Wo >> 1;
    const int tile = blockIdx.x, co0 = blockIdx.y * CO_BLK, n = blockIdx.z;
    const int quads = (Ho * Wo) >> 2;
    const int q0 = tile << 8;
    const int nq = imin(256, quads - q0);
    const int tid = threadIdx.x;
    const int r_first = (q0 << 2) / Wo;
    const int r_last  = (((q0 + nq - 1) << 2) + 3) / Wo;
    const int irs0 = (r_first >> 1) - 1;
    const int nrows = (r_last >> 1) + 1 - irs0 + 1;
    const int W2 = Wi + 2;
    const int nst = nrows * W2;
    const int HWi = Hi * Wi;

    int oh = 0, ow0 = 0;
    if (tid < nq) { const int p = (q0 + tid) << 2; oh = p / Wo; ow0 = p - oh * Wo; }
    const int hpar = oh & 1;
    const int ih_a = (oh >> 1) - 1 + hpar;
    const int la = (ih_a - irs0) * W2 + (ow0 >> 1);

    float acc[CO_BLK][4];
    #pragma unroll
    for (int j = 0; j < CO_BLK; ++j) { acc[j][0]=acc[j][1]=acc[j][2]=acc[j][3]=0.f; }

    for (int ci = 0; ci < Ci; ++ci) {
        const float* src = X + ((size_t)n * Ci + ci) * HWi;
        __syncthreads();
        for (int i = tid; i < nst; i += 256) {
            const int lr = i / W2, c = i - lr * W2;
            const int gr = irs0 + lr, gc = c - 1;
            float v = 0.f;
            if ((unsigned)gr < (unsigned)Hi && (unsigned)gc < (unsigned)Wi)
                v = src[gr * Wi + gc];
            lds[i] = v;
        }
        __syncthreads();
        if (tid >= nq) continue;

        const float va0 = lds[la],      va1 = lds[la+1],
                    va2 = lds[la+2],    va3 = lds[la+3];
        const float vb0 = lds[la+W2],   vb1 = lds[la+W2+1],
                    vb2 = lds[la+W2+2], vb3 = lds[la+W2+3];
        const float4* wq = reinterpret_cast<const float4*>(
            Wt + ((size_t)co0 * Ci + ci) * 16);
        #pragma unroll
        for (int j = 0; j < CO_BLK; ++j) {
            const float4 wA = wq[j * Ci * 4 + hpar];
            const float4 wB = wq[j * Ci * 4 + hpar + 2];
            acc[j][0] += va0*wA.x + va1*wA.z + vb0*wB.x + vb1*wB.z;
            acc[j][1] += va1*wA.y + va2*wA.w + vb1*wB.y + vb2*wB.w;
            acc[j][2] += va1*wA.x + va2*wA.z + vb1*wB.x + vb2*wB.z;
            acc[j][3] += va2*wA.y + va3*wA.w + vb2*wB.y + vb3*wB.w;
        }
    }
    if (tid >= nq) return;
    if (OMODE == 0) {
        float* Out = (float*)Ov;
        #pragma unroll
        for (int j = 0; j < CO_BLK; ++j) {
            const float b = Bias[co0 + j];
            float4 o;
            o.x = lrelu_f(acc[j][0] + b); o.y = lrelu_f(acc[j][1] + b);
            o.z = lrelu_f(acc[j][2] + b); o.w = lrelu_f(acc[j][3] + b);
            *reinterpret_cast<float4*>(Out + ((size_t)n * Co + co0 + j) * (size_t)(Ho * Wo)
                                       + ((q0 + tid) << 2)) = o;
        }
    } else {
        ushort_t* Ob = (ushort_t*)Ov;
        #pragma unroll
        for (int x = 0; x < 4; ++x) {
            short8v pk;
            #pragma unroll
            for (int j = 0; j < CO_BLK; ++j)
                pk[j] = (short)bf16r(lrelu_f(acc[j][x] + Bias[co0 + j]));
            const size_t pix = (size_t)n * (Ho * Wo) + ((q0 + tid) << 2) + x;
            *reinterpret_cast<short8v*>(Ob + pix * Co + co0) = pk;
        }
    }
}

// ===========================================================================
extern "C" void kernel_launch(void* const* d_in, const int* in_sizes, int n_in,
                              void* d_out, int out_size, void* d_ws, size_t ws_size,
                              hipStream_t stream)
{
    const float* h1    = (const float*)d_in[0];
    const float* h2    = (const float*)d_in[1];
    const float* h3    = (const float*)d_in[2];
    const float* y     = (const float*)d_in[3];
    const float* ew1   = (const float*)d_in[4];  const float* eb1 = (const float*)d_in[5];
    const float* ew2   = (const float*)d_in[6];  const float* eb2 = (const float*)d_in[7];
    const float* ew3   = (const float*)d_in[8];  const float* eb3 = (const float*)d_in[9];
    const float* g3wg  = (const float*)d_in[10]; const float* g3bg = (const float*)d_in[11];
    const float* g3wc  = (const float*)d_in[12]; const float* g3bc = (const float*)d_in[13];
    const float* g2wg  = (const float*)d_in[14]; const float* g2bg = (const float*)d_in[15];
    const float* g2wc  = (const float*)d_in[16]; const float* g2bc = (const float*)d_in[17];
    const float* g1wg  = (const float*)d_in[18]; const float* g1bg = (const float*)d_in[19];
    const float* g1wc  = (const float*)d_in[20]; const float* g1bc = (const float*)d_in[21];
    const float* s3w   = (const float*)d_in[22]; const float* s3b  = (const float*)d_in[23];
    const float* s2w   = (const float*)d_in[24]; const float* s2b  = (const float*)d_in[25];
    const float* s1w   = (const float*)d_in[26]; const float* s1b  = (const float*)d_in[27];
    const float* hwt   = (const float*)d_in[28]; const float* hbs  = (const float*)d_in[29];
    float* out = (float*)d_out;
    (void)in_sizes; (void)n_in; (void)out_size; (void)ws_size;

    float* ws = (float*)d_ws;
    size_t off = 0;
    auto alloc = [&](size_t nf) { float* p = ws + off; off += (nf + 15) & ~(size_t)15; return p; };

    // big fp32 scratch (also aliased by encoder temporaries)
    float* gbuf = alloc((size_t)16*2304*128);            // gates NHWC f32 (max level)
    float* cnd  = alloc((size_t)16*9216*16);             // cand NHWC f32 (max)
    float* obuf = alloc((size_t)16*8*36864);             // deconv1 out NCHW f32
    // states: NHWC f32 master, NHWC bf16, NCHW f32
    float* hm1 = alloc((size_t)16*9216*16);
    float* hm2 = alloc((size_t)16*2304*64);
    float* hm3 = alloc((size_t)16*576*96);
    float* hn1 = alloc((size_t)16*16*9216);
    float* hn2 = alloc((size_t)16*64*2304);
    float* hn3 = alloc((size_t)16*96*576);
    ushort_t* hb1 = (ushort_t*)alloc((size_t)16*9216*16/2);
    ushort_t* hb2 = (ushort_t*)alloc((size_t)16*2304*64/2);
    ushort_t* hb3 = (ushort_t*)alloc((size_t)16*576*96/2);
    ushort_t* rhb = (ushort_t*)alloc((size_t)16*9216*16/2);   // r*h bf16 NHWC (max)
    ushort_t* obb = (ushort_t*)alloc((size_t)16*2304*64/2);   // deconv out bf16 NHWC (max)
    ushort_t* x3b = (ushort_t*)alloc((size_t)160*576*96/2);   // encoder L3 out, all T
    // swizzled bf16 weights
    ushort_t* g3f = (ushort_t*)alloc((size_t)1728*192/2);
    ushort_t* c3f = (ushort_t*)alloc((size_t)1728*96/2);
    ushort_t* g2f = (ushort_t*)alloc((size_t)1152*128/2);
    ushort_t* c2f = (ushort_t*)alloc((size_t)1152*64/2);
    ushort_t* g1f = (ushort_t*)alloc((size_t)288*32/2);
    ushort_t* c1f = (ushort_t*)alloc((size_t)288*16/2);
    float* be1 = obuf;                                   // encoder temps alias scan bufs
    float* be2 = gbuf;

    const int T = 10;

    // ---- weight swizzle + state init ----
    wprep_k<192,192><<<(9*192*192+255)/256, 256, 0, stream>>>(g3wg, g3f);
    wprep_k<192, 96><<<(9*192* 96+255)/256, 256, 0, stream>>>(g3wc, c3f);
    wprep_k<128,128><<<(9*128*128+255)/256, 256, 0, stream>>>(g2wg, g2f);
    wprep_k<128, 64><<<(9*128* 64+255)/256, 256, 0, stream>>>(g2wc, c2f);
    wprep_k< 32, 32><<<(9* 32* 32+255)/256, 256, 0, stream>>>(g1wg, g1f);
    wprep_k< 32, 16><<<(9* 32* 16+255)/256, 256, 0, stream>>>(g1wc, c1f);
    init_state_k<16,9216><<<(16*16*9216+255)/256, 256, 0, stream>>>(h1, hm1, hb1, hn1);
    init_state_k<64,2304><<<(16*64*2304+255)/256, 256, 0, stream>>>(h2, hm2, hb2, hn2);
    init_state_k<96, 576><<<(16*96* 576+255)/256, 256, 0, stream>>>(h3, hm3, hb3, hn3);

    // ---- encoder ----
    auto s2c0 = [&](const float* X, int xsn, const float* Wt, const float* Bs,
                    float* O, int Ci, int Co, int Ho, int Wo) {
        const int quads = Ho * Wo / 4, tiles = (quads + 255) / 256;
        const int outSpan = imin(Ho, 1024 / Wo + 2);
        const size_t smem = (size_t)(2 * outSpan + 1) * (2 * Wo + 1) * sizeof(float);
        dim3 g(tiles, Co / 8, 16);
        conv3x3_s2_t<8,0><<<g,256,smem,stream>>>(X,xsn,Wt,Bs,O,Ci,Co,Ho,Wo);
    };
    for (int t = 0; t < T; ++t) {
        s2c0(y + (size_t)t*36864, 10*36864, ew1, eb1, be1, 1, 16, 96, 96);
        s2c0(be1, 16*9216, ew2, eb2, be2, 16, 64, 48, 48);
        {   // enc3 -> NHWC bf16
            const int quads = 24*24/4, tiles = (quads + 255) / 256;
            const size_t smem = (size_t)(2*24 + 1) * (2*24 + 1) * sizeof(float);
            dim3 g(tiles, 96/8, 16);
            conv3x3_s2_t<8,1><<<g,256,smem,stream>>>(
                be2, 64*2304, ew3, eb3, x3b + (size_t)t*16*576*96, 64, 96, 24, 24);
        }
    }

    // ---- scan ----
    auto dcv = [&](const float* X, const float* Wt, const float* Bs,
                   void* O, int Ci, int Co, int Ho, int Wo, int mode) {
        const int quads = Ho * Wo / 4, tiles = (quads + 255) / 256;
        const int outSpan = imin(Ho, 1024 / Wo + 2);
        const size_t smem = (size_t)(outSpan / 2 + 4) * (Wo / 2 + 2) * sizeof(float);
        dim3 g(tiles, Co / 8, 16);
        if (mode == 0)
            deconv4x4_s2_t<8,0><<<g,256,smem,stream>>>(X,Wt,Bs,O,Ci,Co,Ho,Wo);
        else
            deconv4x4_s2_t<8,1><<<g,256,smem,stream>>>(X,Wt,Bs,O,Ci,Co,Ho,Wo);
    };

    for (int t = 0; t < T; ++t) {
        const ushort_t* x3t = x3b + (size_t)t*16*576*96;

        // --- GRU3 @24x24, Cx=Ch=96 ---
        conv3x3_mfma<24,24,96,96,192, 1,4,192, 1>
            <<<dim3(144,3), 256, 192*64*2, stream>>>(x3t, hb3, g3f, g3bg, gbuf);
        rh_t<96><<<(16*576*96+255)/256, 256, 0, stream>>>(gbuf, hm3, rhb, 16*576*96);
        conv3x3_mfma<24,24,96,96, 96, 1,2,192, 2>
            <<<dim3(144,3), 256, 192*32*2, stream>>>(x3t, rhb, c3f, g3bc, cnd);
        upd_t<96,576><<<(16*576*96+255)/256, 256, 0, stream>>>(gbuf, cnd, hm3, hb3, hn3);
        dcv(hn3, s3w, s3b, obb, 96, 64, 48, 48, 1);

        // --- GRU2 @48x48, Cx=Ch=64 ---
        conv3x3_mfma<48,48,64,64,128, 2,4,128, 1>
            <<<dim3(288,2), 256, 128*64*2, stream>>>(obb, hb2, g2f, g2bg, gbuf);
        rh_t<64><<<(16*2304*64+255)/256, 256, 0, stream>>>(gbuf, hm2, rhb, 16*2304*64);
        conv3x3_mfma<48,48,64,64, 64, 2,2,128, 2>
            <<<dim3(288,2), 256, 128*32*2, stream>>>(obb, rhb, c2f, g2bc, cnd);
        upd_t<64,2304><<<(16*2304*64+255)/256, 256, 0, stream>>>(gbuf, cnd, hm2, hb2, hn2);
        dcv(hn2, s2w, s2b, obb, 64, 16, 96, 96, 1);

        // --- GRU1 @96x96, Cx=Ch=16 ---
        conv3x3_mfma<96,96,16,16, 32, 2,2,288, 1>
            <<<dim3(1152,1), 256, 288*32*2, stream>>>(obb, hb1, g1f, g1bg, gbuf);
        rh_t<16><<<(16*9216*16+255)/256, 256, 0, stream>>>(gbuf, hm1, rhb, 16*9216*16);
        conv3x3_mfma<96,96,16,16, 16, 2,1,288, 2>
            <<<dim3(1152,1), 256, 288*16*2, stream>>>(obb, rhb, c1f, g1bc, cnd);
        upd_t<16,9216><<<(16*9216*16+255)/256, 256, 0, stream>>>(gbuf, cnd, hm1, hb1, hn1);
        dcv(hn1, s1w, s1b, obuf, 16, 8, 192, 192, 0);

        // --- head conv (fp32, Co=1) ---
        {
            const int quads = 192*192/4, tiles = (quads + 255) / 256;
            const size_t smem = (size_t)9 * 194 * sizeof(float);
            dim3 g(tiles, 1, 16);
            conv3x3_s1_t<0,1><<<g,256,smem,stream>>>(
                obuf, 8*36864, (const float*)nullptr, hwt, hbs,
                out + (size_t)t*16*36864, 8, 0, 1, 192, 192);
        }
    }
}

// Round 5
// 2708.458 us; speedup vs baseline: 17.7776x; 3.6885x over previous
//
#include <hip/hip_runtime.h>

typedef unsigned short ushort_t;
typedef __attribute__((ext_vector_type(8))) short short8v;
typedef __attribute__((ext_vector_type(4))) float f32x4;

__device__ __forceinline__ float lrelu_f(float x) { return x > 0.f ? x : 0.2f * x; }
__device__ __forceinline__ float sigm_f(float x)  { return 1.f / (1.f + __expf(-x)); }
__device__ __forceinline__ ushort_t bf16r(float f) {
    union { float f; unsigned int u; } x; x.f = f;
    unsigned int r = x.u + 0x7FFFu + ((x.u >> 16) & 1u);
    return (ushort_t)(r >> 16);
}
__host__ __device__ static inline int imin(int a, int b) { return a < b ? a : b; }

// ===========================================================================
// Unified MFMA implicit-GEMM conv kernel. NHWC bf16 in, 16x16x32 bf16 MFMA.
// k = tap*Ci + c (Ci = Cx+Chn). B pre-swizzled [k/8][CoW][8].
// STRIDE 1: ih=oh+dh (pad 1);  STRIDE 2: ih=2*oh+kh (pad (0,1)).
// EPI: 0 gate  (sigm; z->aux0 [pix][C] f32, r*hm->aux2 [pix][C] bf16; C=CoW/2)
//      1 cand  (lrelu; h'=(1-z)h+z*c -> aux1 f32 [pix][CoW] & aux2 bf16)
//      2 plain (lrelu -> aux2 bf16 NHWC [pix][CoW])
//      3 dconv (lrelu -> aux2 bf16 NHWC 2H x 2W x CoW/4, parity scatter)
//      4 dconv (lrelu -> aux0 f32  NCHW 2H x 2W x CoW/4, parity scatter)
// ===========================================================================
template<int Hin, int Win, int Cx, int Chn, int STRIDE, int CoW,
         int MT, int NTB, int KC, int NCH, int K_REAL, int EPI>
__global__ __launch_bounds__(256) void mconv(
    const ushort_t* __restrict__ Xp, const ushort_t* __restrict__ Hp,
    const ushort_t* __restrict__ Wf, const float* __restrict__ Bias,
    float* __restrict__ aux0, float* __restrict__ aux1, ushort_t* __restrict__ aux2)
{
    constexpr int Ci  = Cx + Chn;
    constexpr int NCO = NTB * 16;
    constexpr int Ho  = Hin / STRIDE, Wo = Win / STRIDE;
    constexpr int HWo = Ho * Wo;
    extern __shared__ ushort_t bsh[];

    const int tid = threadIdx.x;
    const int wv = tid >> 6, ln = tid & 63;
    const int llo = ln & 15, lhi = ln >> 4;
    const int co0 = blockIdx.y * NCO;

    int rowb[MT][10];
    unsigned vmask[MT];
    #pragma unroll
    for (int mt = 0; mt < MT; ++mt) {
        const int mtile = (blockIdx.x * 4 + wv) * MT + mt;
        const int gp = mtile * 16 + llo;
        const int n = gp / HWo, p = gp % HWo;
        const int oh = p / Wo, ow = p % Wo;
        vmask[mt] = 0u;
        #pragma unroll
        for (int tap = 0; tap < 9; ++tap) {
            int ih, iw; bool ok;
            if (STRIDE == 1) {
                ih = oh + tap / 3 - 1; iw = ow + tap % 3 - 1;
                ok = ((unsigned)ih < (unsigned)Hin) && ((unsigned)iw < (unsigned)Win);
            } else {
                ih = 2 * oh + tap / 3; iw = 2 * ow + tap % 3;
                ok = (ih < Hin) && (iw < Win);
            }
            rowb[mt][tap] = (n * Hin + ih) * Win + iw;
            if (ok) vmask[mt] |= 1u << tap;
        }
        rowb[mt][9] = 0;
    }

    f32x4 acc[MT][NTB];
    #pragma unroll
    for (int mt = 0; mt < MT; ++mt)
        #pragma unroll
        for (int nt = 0; nt < NTB; ++nt)
            acc[mt][nt] = f32x4{0.f, 0.f, 0.f, 0.f};

    #pragma unroll
    for (int ch = 0; ch < NCH; ++ch) {
        __syncthreads();
        constexpr int UNITS = (KC / 8) * NCO;
        for (int u = tid; u < UNITS; u += 256) {
            const int kb = u / NCO, col = u % NCO;
            const ushort_t* src = Wf + ((size_t)(ch * (KC / 8) + kb) * CoW + co0 + col) * 8;
            *reinterpret_cast<short8v*>(&bsh[(size_t)u * 8]) =
                *reinterpret_cast<const short8v*>(src);
        }
        __syncthreads();

        #pragma unroll
        for (int kk = 0; kk < KC / 32; ++kk) {
            const int gk = ch * KC + kk * 32;
            if (gk >= K_REAL) continue;
            short8v a[MT];
            if constexpr (Ci % 32 == 0) {
                const int tap = gk / Ci;
                const int c   = gk % Ci + lhi * 8;
                #pragma unroll
                for (int mt = 0; mt < MT; ++mt) {
                    a[mt] = short8v{0,0,0,0,0,0,0,0};
                    if ((vmask[mt] >> tap) & 1u) {
                        const int rb = rowb[mt][tap];
                        const ushort_t* ap = (c < Cx)
                            ? (Xp + (size_t)rb * Cx + c)
                            : (Hp + (size_t)rb * Chn + (c - Cx));
                        a[mt] = *reinterpret_cast<const short8v*>(ap);
                    }
                }
            } else {  // Ci == 16, single source Xp
                const int tap0 = gk >> 4;
                const int c16  = (lhi & 1) * 8;
                const bool hi  = (lhi >= 2);
                #pragma unroll
                for (int mt = 0; mt < MT; ++mt) {
                    const int rb   = hi ? rowb[mt][tap0 + 1] : rowb[mt][tap0];
                    const bool ok  = ((vmask[mt] >> (hi ? tap0 + 1 : tap0)) & 1u) != 0u;
                    a[mt] = short8v{0,0,0,0,0,0,0,0};
                    if (ok)
                        a[mt] = *reinterpret_cast<const short8v*>(Xp + (size_t)rb * 16 + c16);
                }
            }
            #pragma unroll
            for (int nt = 0; nt < NTB; ++nt) {
                const short8v b = *reinterpret_cast<const short8v*>(
                    &bsh[((size_t)(kk * 4 + lhi) * NCO + nt * 16 + llo) * 8]);
                #pragma unroll
                for (int mt = 0; mt < MT; ++mt)
                    acc[mt][nt] = __builtin_amdgcn_mfma_f32_16x16x32_bf16(
                        a[mt], b, acc[mt][nt], 0, 0, 0);
            }
        }
    }

    #pragma unroll
    for (int mt = 0; mt < MT; ++mt) {
        const int mtile = (blockIdx.x * 4 + wv) * MT + mt;
        #pragma unroll
        for (int nt = 0; nt < NTB; ++nt) {
            const int cog = co0 + nt * 16 + llo;
            float bias;
            if (EPI == 3 || EPI == 4) bias = Bias[cog % (CoW / 4)];
            else bias = Bias[cog];
            #pragma unroll
            for (int r = 0; r < 4; ++r) {
                const int opix = mtile * 16 + lhi * 4 + r;
                float v = acc[mt][nt][r] + bias;
                if (EPI == 0) {
                    v = sigm_f(v);
                    constexpr int C = CoW / 2;
                    if (cog < C) aux0[(size_t)opix * C + cog] = v;
                    else {
                        const int c2 = cog - C;
                        aux2[(size_t)opix * C + c2] =
                            bf16r(v * aux1[(size_t)opix * C + c2]);
                    }
                } else if (EPI == 1) {
                    v = lrelu_f(v);
                    const float z = aux0[(size_t)opix * CoW + cog];
                    const float h = aux1[(size_t)opix * CoW + cog];
                    const float nh = (1.f - z) * h + z * v;
                    aux1[(size_t)opix * CoW + cog] = nh;
                    aux2[(size_t)opix * CoW + cog] = bf16r(nh);
                } else if (EPI == 2) {
                    aux2[(size_t)opix * CoW + cog] = bf16r(lrelu_f(v));
                } else {
                    v = lrelu_f(v);
                    constexpr int CoR = CoW / 4;
                    const int pq = cog / CoR, co = cog % CoR;
                    const int p2 = pq >> 1, q2 = pq & 1;
                    const int n = opix / HWo, pp = opix % HWo;
                    const int ih = pp / Win, iw = pp % Win;
                    const int oh2 = 2 * ih + p2, ow2 = 2 * iw + q2;
                    if (EPI == 3)
                        aux2[(((size_t)n * (2 * Hin) + oh2) * (2 * Win) + ow2) * CoR + co] = bf16r(v);
                    else
                        aux0[(((size_t)n * CoR + co) * (2 * Hin) + oh2) * (2 * Win) + ow2] = v;
                }
            }
        }
    }
}

// ===========================================================================
// Weight swizzles
// ===========================================================================
template<int CiT, int Co, int KPAD>
__global__ void wprep_k(const float* __restrict__ Wsrc, ushort_t* __restrict__ Wf)
{
    const int total = KPAD * Co;
    int i = blockIdx.x * blockDim.x + threadIdx.x;
    if (i >= total) return;
    const int k = i / Co, co = i % Co;
    float v = 0.f;
    if (k < 9 * CiT) {
        const int tap = k / CiT, ci = k % CiT;
        v = Wsrc[((size_t)co * CiT + ci) * 9 + tap];
    }
    Wf[(size_t)(k >> 3) * Co * 8 + co * 8 + (k & 7)] = bf16r(v);
}

// deconv 4x4 s2 -> padded 3x3 conv with Co'=4*CoR parity expansion
template<int Ci, int CoR, int KPAD>
__global__ void wprep_dcv(const float* __restrict__ Wsrc, ushort_t* __restrict__ Wf)
{
    constexpr int CoW = 4 * CoR;
    const int total = KPAD * CoW;
    int i = blockIdx.x * blockDim.x + threadIdx.x;
    if (i >= total) return;
    const int k = i / CoW, cop = i % CoW;
    float v = 0.f;
    if (k < 9 * Ci) {
        const int tap = k / Ci, ci = k % Ci;
        const int dh = tap / 3 - 1, dw = tap % 3 - 1;
        const int pq = cop / CoR, co = cop % CoR;
        const int p = pq >> 1, q = pq & 1;
        int kh = -1, kw = -1;
        if (p == 0) { if (dh == -1) kh = 0; else if (dh == 0) kh = 2; }
        else        { if (dh ==  0) kh = 1; else if (dh == 1) kh = 3; }
        if (q == 0) { if (dw == -1) kw = 0; else if (dw == 0) kw = 2; }
        else        { if (dw ==  0) kw = 1; else if (dw == 1) kw = 3; }
        if (kh >= 0 && kw >= 0)
            v = Wsrc[(((size_t)co * Ci + ci) * 4 + kh) * 4 + kw];
    }
    Wf[(size_t)(k >> 3) * CoW * 8 + cop * 8 + (k & 7)] = bf16r(v);
}

// NCHW f32 state -> NHWC f32 + NHWC bf16
template<int Ch, int HW>
__global__ void init_state_k(const float* __restrict__ src,
                             float* __restrict__ hm, ushort_t* __restrict__ hb)
{
    const int total = 16 * Ch * HW;
    int i = blockIdx.x * blockDim.x + threadIdx.x;
    if (i >= total) return;
    const int n = i / (Ch * HW);
    const int rem = i % (Ch * HW);
    const int c = rem / HW, p = rem % HW;
    const float v = src[i];
    const size_t pix = (size_t)n * HW + p;
    hm[pix * Ch + c] = v;
    hb[pix * Ch + c] = bf16r(v);
}

// ===========================================================================
// Encoder conv1: 1ch 192x192 -> 16ch 96x96 stride-2 (fp32 math, bf16 NHWC out)
// frame f = t*16+b reads y[b][t]; all 160 frames in one launch (z=160).
// ===========================================================================
__global__ __launch_bounds__(256) void enc1_k(
    const float* __restrict__ Y, const float* __restrict__ Wt,
    const float* __restrict__ Bias, ushort_t* __restrict__ Ob)
{
    extern __shared__ float lds[];
    const int tile = blockIdx.x, co0 = blockIdx.y * 8, f = blockIdx.z;
    const int tid = threadIdx.x;
    const float* src = Y + (size_t)(f & 15) * 368640 + (size_t)(f >> 4) * 36864;
    const int q0 = tile << 8;
    const int r_first = (q0 << 2) / 96, r_last = ((q0 << 2) + 1023) / 96;
    const int irs0 = r_first << 1;
    const int nrows = (r_last << 1) + 3 - irs0;
    const int nst = nrows * 193;
    for (int i = tid; i < nst; i += 256) {
        const int lr = i / 193, c = i - lr * 193;
        const int gr = irs0 + lr;
        float v = 0.f;
        if (gr < 192 && c < 192) v = src[gr * 192 + c];
        lds[i] = v;
    }
    __syncthreads();
    const int p = (q0 + tid) << 2;
    const int oh = p / 96, ow0 = p - oh * 96;
    const float* l0 = lds + ((oh << 1) - irs0) * 193 + (ow0 << 1);
    float u0[9], u1[9], u2[9];
    #pragma unroll
    for (int x = 0; x < 9; ++x) {
        u0[x] = l0[x]; u1[x] = l0[193 + x]; u2[x] = l0[386 + x];
    }
    float acc[8][4];
    #pragma unroll
    for (int j = 0; j < 8; ++j) {
        const float* w = Wt + (size_t)(co0 + j) * 9;
        const float w0=w[0],w1=w[1],w2=w[2],w3=w[3],w4=w[4],w5=w[5],w6=w[6],w7=w[7],w8=w[8];
        #pragma unroll
        for (int x = 0; x < 4; ++x)
            acc[j][x] = u0[2*x]*w0 + u0[2*x+1]*w1 + u0[2*x+2]*w2
                      + u1[2*x]*w3 + u1[2*x+1]*w4 + u1[2*x+2]*w5
                      + u2[2*x]*w6 + u2[2*x+1]*w7 + u2[2*x+2]*w8;
    }
    #pragma unroll
    for (int x = 0; x < 4; ++x) {
        short8v pk;
        #pragma unroll
        for (int j = 0; j < 8; ++j)
            pk[j] = (short)bf16r(lrelu_f(acc[j][x] + Bias[co0 + j]));
        *reinterpret_cast<short8v*>(Ob + ((size_t)f * 9216 + p + x) * 16 + co0) = pk;
    }
}

// ===========================================================================
// fp32 tiled stride-1 conv (head, Co=1, NCHW f32 in/out)
// ===========================================================================
template<int ACT, int CO_BLK>
__global__ __launch_bounds__(256) void conv3x3_s1_t(
    const float* __restrict__ X, int xStrideN,
    const float* __restrict__ Hs,
    const float* __restrict__ Wt, const float* __restrict__ Bias,
    float* __restrict__ Out,
    int Cx, int Ch, int Co, int HH, int WW)
{
    extern __shared__ float lds[];
    const int tile = blockIdx.x, co0 = blockIdx.y * CO_BLK, n = blockIdx.z;
    const int Ci = Cx + Ch;
    const int HW = HH * WW;
    const int quads = HW >> 2;
    const int q0 = tile << 8;
    const int nq = imin(256, quads - q0);
    const int tid = threadIdx.x;
    const int r_first = (q0 << 2) / WW;
    const int r_last  = (((q0 + nq - 1) << 2) + 3) / WW;
    const int rs0 = r_first - 1;
    const int nrows = r_last - r_first + 3;
    const int W2 = WW + 2;
    const int nst = nrows * W2;

    int oh = 0, ow0 = 0, lbase = 0;
    if (tid < nq) {
        const int p = (q0 + tid) << 2;
        oh = p / WW; ow0 = p - oh * WW;
        lbase = (oh - r_first) * W2 + ow0;
    }

    float acc[CO_BLK][4];
    #pragma unroll
    for (int j = 0; j < CO_BLK; ++j) { acc[j][0]=acc[j][1]=acc[j][2]=acc[j][3]=0.f; }

    for (int ci = 0; ci < Ci; ++ci) {
        const float* src = (ci < Cx)
            ? (X + (size_t)n * xStrideN + (size_t)ci * HW)
            : (Hs + ((size_t)n * Ch + (size_t)(ci - Cx)) * HW);
        __syncthreads();
        for (int i = tid; i < nst; i += 256) {
            const int lr = i / W2, c = i - lr * W2;
            const int gr = rs0 + lr, gc = c - 1;
            float v = 0.f;
            if ((unsigned)gr < (unsigned)HH && (unsigned)gc < (unsigned)WW)
                v = src[gr * WW + gc];
            lds[i] = v;
        }
        __syncthreads();
        if (tid >= nq) continue;

        float v0[6], v1[6], v2[6];
        const float* l0 = lds + lbase;
        #pragma unroll
        for (int x = 0; x < 6; ++x) {
            v0[x] = l0[x]; v1[x] = l0[W2 + x]; v2[x] = l0[2 * W2 + x];
        }
        const float* wb = Wt + ((size_t)co0 * Ci + ci) * 9;
        #pragma unroll
        for (int j = 0; j < CO_BLK; ++j) {
            const float* w = wb + (size_t)j * Ci * 9;
            const float w0=w[0],w1=w[1],w2=w[2],w3=w[3],w4=w[4],
                        w5=w[5],w6=w[6],w7=w[7],w8=w[8];
            #pragma unroll
            for (int x = 0; x < 4; ++x)
                acc[j][x] += v0[x]*w0 + v0[x+1]*w1 + v0[x+2]*w2
                           + v1[x]*w3 + v1[x+1]*w4 + v1[x+2]*w5
                           + v2[x]*w6 + v2[x+1]*w7 + v2[x+2]*w8;
        }
    }
    if (tid >= nq) return;
    #pragma unroll
    for (int j = 0; j < CO_BLK; ++j) {
        const float b = Bias[co0 + j];
        float4 o;
        o.x = acc[j][0] + b; o.y = acc[j][1] + b;
        o.z = acc[j][2] + b; o.w = acc[j][3] + b;
        if (ACT == 1) { o.x=sigm_f(o.x); o.y=sigm_f(o.y); o.z=sigm_f(o.z); o.w=sigm_f(o.w); }
        else if (ACT == 2) { o.x=lrelu_f(o.x); o.y=lrelu_f(o.y); o.z=lrelu_f(o.z); o.w=lrelu_f(o.w); }
        *reinterpret_cast<float4*>(Out + ((size_t)n * Co + co0 + j) * HW + ((q0 + tid) << 2)) = o;
    }
}

// ===========================================================================
extern "C" void kernel_launch(void* const* d_in, const int* in_sizes, int n_in,
                              void* d_out, int out_size, void* d_ws, size_t ws_size,
                              hipStream_t stream)
{
    const float* h1    = (const float*)d_in[0];
    const float* h2    = (const float*)d_in[1];
    const float* h3    = (const float*)d_in[2];
    const float* y     = (const float*)d_in[3];
    const float* ew1   = (const float*)d_in[4];  const float* eb1 = (const float*)d_in[5];
    const float* ew2   = (const float*)d_in[6];  const float* eb2 = (const float*)d_in[7];
    const float* ew3   = (const float*)d_in[8];  const float* eb3 = (const float*)d_in[9];
    const float* g3wg  = (const float*)d_in[10]; const float* g3bg = (const float*)d_in[11];
    const float* g3wc  = (const float*)d_in[12]; const float* g3bc = (const float*)d_in[13];
    const float* g2wg  = (const float*)d_in[14]; const float* g2bg = (const float*)d_in[15];
    const float* g2wc  = (const float*)d_in[16]; const float* g2bc = (const float*)d_in[17];
    const float* g1wg  = (const float*)d_in[18]; const float* g1bg = (const float*)d_in[19];
    const float* g1wc  = (const float*)d_in[20]; const float* g1bc = (const float*)d_in[21];
    const float* s3w   = (const float*)d_in[22]; const float* s3b  = (const float*)d_in[23];
    const float* s2w   = (const float*)d_in[24]; const float* s2b  = (const float*)d_in[25];
    const float* s1w   = (const float*)d_in[26]; const float* s1b  = (const float*)d_in[27];
    const float* hwt   = (const float*)d_in[28]; const float* hbs  = (const float*)d_in[29];
    float* out = (float*)d_out;
    (void)in_sizes; (void)n_in; (void)out_size; (void)ws_size;

    float* ws = (float*)d_ws;
    size_t off = 0;
    auto alloc = [&](size_t nf) { float* p = ws + off; off += (nf + 15) & ~(size_t)15; return p; };

    // union1: encoder e1b (160*9216*16 bf16 = 11,796,480 f) | scan {gbuf,obuf,rhb,obb}
    float* u1 = alloc(11796480);
    // union2: encoder e2b (160*2304*64 bf16 = 11,796,480 f) | states {hm*,hb*}
    float* u2 = alloc(11796480);
    ushort_t* x3b = (ushort_t*)alloc(4423680);   // 160*576*96 bf16

    ushort_t* e1b = (ushort_t*)u1;
    float*    gbuf = u1;                          // z gates [pix][C] f32, max 2,359,296
    float*    obuf = u1 + 2359296;                // deconv1 NCHW f32, 4,718,592
    ushort_t* rhb  = (ushort_t*)(u1 + 7077888);   // r*h bf16 NHWC, max 1,179,648 f
    ushort_t* obb  = (ushort_t*)(u1 + 8257536);   // deconv bf16 NHWC, max 1,179,648 f

    ushort_t* e2b = (ushort_t*)u2;
    float* hm1 = u2;               // 2,359,296
    float* hm2 = u2 + 2359296;     // 2,359,296
    float* hm3 = u2 + 4718592;     //   884,736
    ushort_t* hb1 = (ushort_t*)(u2 + 5603328);
    ushort_t* hb2 = (ushort_t*)(u2 + 6782976);
    ushort_t* hb3 = (ushort_t*)(u2 + 7962624);

    ushort_t* g3f = (ushort_t*)alloc(165888);
    ushort_t* c3f = (ushort_t*)alloc(82944);
    ushort_t* g2f = (ushort_t*)alloc(73728);
    ushort_t* c2f = (ushort_t*)alloc(36864);
    ushort_t* g1f = (ushort_t*)alloc(4608);
    ushort_t* c1f = (ushort_t*)alloc(2304);
    ushort_t* e2w = (ushort_t*)alloc(5120);
    ushort_t* e3w = (ushort_t*)alloc(27648);
    ushort_t* d3f = (ushort_t*)alloc(110592);
    ushort_t* d2f = (ushort_t*)alloc(18432);
    ushort_t* d1f = (ushort_t*)alloc(2560);

    const int T = 10;

    // ---- weight swizzles ----
    wprep_k<192,192,1728><<<(1728*192+255)/256,256,0,stream>>>(g3wg, g3f);
    wprep_k<192, 96,1728><<<(1728* 96+255)/256,256,0,stream>>>(g3wc, c3f);
    wprep_k<128,128,1152><<<(1152*128+255)/256,256,0,stream>>>(g2wg, g2f);
    wprep_k<128, 64,1152><<<(1152* 64+255)/256,256,0,stream>>>(g2wc, c2f);
    wprep_k< 32, 32, 288><<<( 288* 32+255)/256,256,0,stream>>>(g1wg, g1f);
    wprep_k< 32, 16, 288><<<( 288* 16+255)/256,256,0,stream>>>(g1wc, c1f);
    wprep_k< 16, 64, 160><<<( 160* 64+255)/256,256,0,stream>>>(ew2, e2w);
    wprep_k< 64, 96, 576><<<( 576* 96+255)/256,256,0,stream>>>(ew3, e3w);
    wprep_dcv<96,64,864><<<(864*256+255)/256,256,0,stream>>>(s3w, d3f);
    wprep_dcv<64,16,576><<<(576* 64+255)/256,256,0,stream>>>(s2w, d2f);
    wprep_dcv<16, 8,160><<<(160* 32+255)/256,256,0,stream>>>(s1w, d1f);

    // ---- encoder (all 160 frames per layer) ----
    enc1_k<<<dim3(9,2,160), 256, 19328, stream>>>(y, ew1, eb1, e1b);
    // conv2: 96x96x16 -s2-> 48x48x64
    mconv<96,96,16,0,2, 64, 2,4,160,1,144, 2>
        <<<dim3(2880,1), 256, 160*64*2, stream>>>(e1b, nullptr, e2w, eb2,
                                                  nullptr, nullptr, e2b);
    // conv3: 48x48x64 -s2-> 24x24x96
    mconv<48,48,64,0,2, 96, 1,6,192,3,576, 2>
        <<<dim3(1440,1), 256, 192*96*2, stream>>>(e2b, nullptr, e3w, eb3,
                                                  nullptr, nullptr, x3b);

    // ---- init states (after encoder: union2 freed) ----
    init_state_k<16,9216><<<(16*16*9216+255)/256,256,0,stream>>>(h1, hm1, hb1);
    init_state_k<64,2304><<<(16*64*2304+255)/256,256,0,stream>>>(h2, hm2, hb2);
    init_state_k<96, 576><<<(16*96* 576+255)/256,256,0,stream>>>(h3, hm3, hb3);

    // ---- scan ----
    for (int t = 0; t < T; ++t) {
        const ushort_t* x3t = x3b + (size_t)t * 16 * 576 * 96;

        // GRU3 @24x24 (Cx=Ch=96)
        mconv<24,24,96,96,1,192, 1,4,192,9,1728, 0>
            <<<dim3(144,3), 256, 192*64*2, stream>>>(x3t, hb3, g3f, g3bg, gbuf, hm3, rhb);
        mconv<24,24,96,96,1, 96, 1,2,192,9,1728, 1>
            <<<dim3(144,3), 256, 192*32*2, stream>>>(x3t, rhb, c3f, g3bc, gbuf, hm3, hb3);
        mconv<24,24,96,0,1,256, 1,4,288,3, 864, 3>
            <<<dim3(144,4), 256, 288*64*2, stream>>>(hb3, nullptr, d3f, s3b,
                                                     nullptr, nullptr, obb);

        // GRU2 @48x48 (Cx=Ch=64)
        mconv<48,48,64,64,1,128, 2,4,128,9,1152, 0>
            <<<dim3(288,2), 256, 128*64*2, stream>>>(obb, hb2, g2f, g2bg, gbuf, hm2, rhb);
        mconv<48,48,64,64,1, 64, 2,2,128,9,1152, 1>
            <<<dim3(288,2), 256, 128*32*2, stream>>>(obb, rhb, c2f, g2bc, gbuf, hm2, hb2);
        mconv<48,48,64,0,1, 64, 2,4,192,3, 576, 3>
            <<<dim3(288,1), 256, 192*64*2, stream>>>(hb2, nullptr, d2f, s2b,
                                                     nullptr, nullptr, obb);

        // GRU1 @96x96 (Cx=Ch=16)
        mconv<96,96,16,16,1, 32, 2,2,288,1, 288, 0>
            <<<dim3(1152,1), 256, 288*32*2, stream>>>(obb, hb1, g1f, g1bg, gbuf, hm1, rhb);
        mconv<96,96,16,16,1, 16, 2,1,288,1, 288, 1>
            <<<dim3(1152,1), 256, 288*16*2, stream>>>(obb, rhb, c1f, g1bc, gbuf, hm1, hb1);
        mconv<96,96,16,0,1, 32, 2,2,160,1, 144, 4>
            <<<dim3(1152,1), 256, 160*32*2, stream>>>(hb1, nullptr, d1f, s1b,
                                                      obuf, nullptr, nullptr);

        // head conv (fp32, Co=1) from obuf NCHW
        {
            const int tiles = (192*192/4 + 255) / 256;
            const size_t smem = (size_t)9 * 194 * sizeof(float);
            dim3 g(tiles, 1, 16);
            conv3x3_s1_t<0,1><<<g,256,smem,stream>>>(
                obuf, 8*36864, (const float*)nullptr, hwt, hbs,
                out + (size_t)t*16*36864, 8, 0, 1, 192, 192);
        }
    }
}